// Round 3
// baseline (432.121 us; speedup 1.0000x reference)
//
#include <hip/hip_runtime.h>
#include <hip/hip_bf16.h>
#include <math.h>

constexpr int B = 2, L = 1024, D = 1024, H = 16, DK = 64;
constexpr int M = B * L;           // 2048 rows
constexpr int DD = D * D;

typedef __attribute__((ext_vector_type(8))) short bf16x8;
typedef __attribute__((ext_vector_type(4))) float f32x4;

__device__ inline unsigned short f2bf(float f) {
    __hip_bfloat16 h = __float2bfloat16(f);
    return __builtin_bit_cast(unsigned short, h);
}

// async global->LDS, 16B per lane; LDS dest = base + lane*16 (wave-uniform base)
__device__ inline void glds16(const void* g, void* l) {
    __builtin_amdgcn_global_load_lds((const __attribute__((address_space(1))) void*)g,
                                     (__attribute__((address_space(3))) void*)l,
                                     16, 0, 0);
}

// ---------------- LayerNorm + lsm: qn16 = LN(query), q16 = bf16(query) ------
__global__ __launch_bounds__(256) void ln2_kernel(const float* __restrict__ x,
                                                  const float* __restrict__ gamma,
                                                  const float* __restrict__ beta,
                                                  const float* __restrict__ lex,
                                                  const int* __restrict__ mask,
                                                  unsigned short* __restrict__ qn16,
                                                  unsigned short* __restrict__ q16,
                                                  float* __restrict__ lsmout) {
    int row = blockIdx.x;
    int t = threadIdx.x;
    if (t == 0) lsmout[row] = mask[row] ? lex[row] : -1e30f;
    const float4 v = ((const float4*)(x + (size_t)row * D))[t];
    float s  = v.x + v.y + v.z + v.w;
    float sq = v.x*v.x + v.y*v.y + v.z*v.z + v.w*v.w;
    #pragma unroll
    for (int m = 32; m >= 1; m >>= 1) {
        s  += __shfl_xor(s, m, 64);
        sq += __shfl_xor(sq, m, 64);
    }
    __shared__ float rs[4], rq[4];
    int wid = t >> 6;
    if ((t & 63) == 0) { rs[wid] = s; rq[wid] = sq; }
    __syncthreads();
    s  = rs[0] + rs[1] + rs[2] + rs[3];
    sq = rq[0] + rq[1] + rq[2] + rq[3];
    float mean = s * (1.0f / D);
    float var  = sq * (1.0f / D) - mean * mean;
    float rstd = rsqrtf(var + 1e-6f);
    float4 g  = ((const float4*)gamma)[t];
    float4 bb = ((const float4*)beta)[t];
    ushort4 on, oq;
    on.x = f2bf((v.x - mean) * rstd * g.x + bb.x);
    on.y = f2bf((v.y - mean) * rstd * g.y + bb.y);
    on.z = f2bf((v.z - mean) * rstd * g.z + bb.z);
    on.w = f2bf((v.w - mean) * rstd * g.w + bb.w);
    oq.x = f2bf(v.x); oq.y = f2bf(v.y); oq.z = f2bf(v.z); oq.w = f2bf(v.w);
    ((ushort4*)(qn16 + (size_t)row * D))[t] = on;
    ((ushort4*)(q16  + (size_t)row * D))[t] = oq;
}

// ---------------- weight cast: 4 x (D,D) fp32 -> bf16 ----------------------
__global__ __launch_bounds__(256) void wconv_kernel(const float* __restrict__ Wq,
                                                    const float* __restrict__ Wk,
                                                    const float* __restrict__ Wv,
                                                    const float* __restrict__ Wo,
                                                    unsigned short* __restrict__ out) {
    const float* src = (blockIdx.y == 0) ? Wq : (blockIdx.y == 1) ? Wk
                       : (blockIdx.y == 2) ? Wv : Wo;
    size_t i = (size_t)blockIdx.x * 256 + threadIdx.x;
    float4 v = ((const float4*)src)[i];
    ushort4 o;
    o.x = f2bf(v.x); o.y = f2bf(v.y); o.z = f2bf(v.z); o.w = f2bf(v.w);
    ((ushort4*)(out + (size_t)blockIdx.y * DD))[i] = o;
}

// ---------------- fused QKV GEMM: 128x128 tile, BK=64, global_load_lds ------
// Swizzled LDS: phys chunk = logical chunk ^ (row&7); rows of 64 shorts, no pad.
__global__ __launch_bounds__(256) void gemm_qkv(
        const unsigned short* __restrict__ qn16, const unsigned short* __restrict__ q16,
        const unsigned short* __restrict__ W,
        const float* __restrict__ bq, const float* __restrict__ bk,
        const float* __restrict__ bv,
        unsigned short* __restrict__ Qm, unsigned short* __restrict__ Km,
        unsigned short* __restrict__ Vm) {
    __shared__ __align__(16) unsigned short As[128 * 64];
    __shared__ __align__(16) unsigned short Ws[128 * 64];
    int t = threadIdx.x, lane = t & 63, w = t >> 6;
    int quad = lane >> 4, l15 = lane & 15;
    int nt = blockIdx.x;                 // 0..23
    int bm = blockIdx.y * 128;
    const unsigned short* A = (nt < 8) ? qn16 : q16;
    const float* bias = (nt < 8) ? bq : ((nt < 16) ? bk : bv);
    unsigned short* Cout = (nt < 8) ? Qm : ((nt < 16) ? Km : Vm);
    int bn_local = (nt & 7) * 128;
    int wm = (w >> 1) * 64, wn = (w & 1) * 64;
    f32x4 acc[4][4] = {};
    for (int k0 = 0; k0 < D; k0 += 64) {
        __syncthreads();
        const unsigned short* ap = A + (size_t)(bm + w * 32) * D + k0;
        const unsigned short* wp = W + (size_t)(nt * 128 + w * 32) * D + k0;
        #pragma unroll
        for (int i = 0; i < 4; i++) {
            int c = i * 64 + lane;
            int r = c >> 3, g = (c & 7) ^ (r & 7);
            glds16(ap + (size_t)r * D + g * 8, &As[w * 2048 + i * 512]);
            glds16(wp + (size_t)r * D + g * 8, &Ws[w * 2048 + i * 512]);
        }
        __syncthreads();
        #pragma unroll
        for (int k2 = 0; k2 < 2; k2++) {
            bf16x8 av[4], bw[4];
            #pragma unroll
            for (int i = 0; i < 4; i++) {
                int r = wm + i * 16 + l15;
                av[i] = *(const bf16x8*)&As[r * 64 + (((quad + 4 * k2) ^ (r & 7)) * 8)];
            }
            #pragma unroll
            for (int j = 0; j < 4; j++) {
                int r = wn + j * 16 + l15;
                bw[j] = *(const bf16x8*)&Ws[r * 64 + (((quad + 4 * k2) ^ (r & 7)) * 8)];
            }
            #pragma unroll
            for (int i = 0; i < 4; i++)
                #pragma unroll
                for (int j = 0; j < 4; j++)
                    acc[i][j] = __builtin_amdgcn_mfma_f32_16x16x32_bf16(av[i], bw[j], acc[i][j], 0, 0, 0);
        }
    }
    #pragma unroll
    for (int j = 0; j < 4; j++) {
        int col = bn_local + wn + j * 16 + l15;
        float bcol = bias[col];
        #pragma unroll
        for (int i = 0; i < 4; i++)
            #pragma unroll
            for (int rg = 0; rg < 4; rg++) {
                int row = bm + wm + i * 16 + quad * 4 + rg;
                Cout[(size_t)row * D + col] = f2bf(acc[i][j][rg] + bcol);
            }
    }
}

// ---------------- V transpose: Vm [b,s,h*64+d] -> Vt [bh][d][s] ------------
__global__ __launch_bounds__(256) void vtrans_kernel(const unsigned short* __restrict__ Vm,
                                                     unsigned short* __restrict__ Vt) {
    __shared__ unsigned short sb[128 * 66];
    int t = threadIdx.x;
    int z = blockIdx.y;
    int b = z >> 4, h = z & 15;
    int s0 = blockIdx.x * 128;
    size_t base = (size_t)b * L * D + (size_t)h * 64;
    #pragma unroll
    for (int i = 0; i < 4; i++) {
        int idx = t + 256 * i;
        int r = idx >> 3, c8 = idx & 7;
        uint4 vv = *(const uint4*)&Vm[base + (size_t)(s0 + r) * D + c8 * 8];
        unsigned int* sp = (unsigned int*)&sb[r * 66 + c8 * 8];
        sp[0] = vv.x; sp[1] = vv.y; sp[2] = vv.z; sp[3] = vv.w;
    }
    __syncthreads();
    #pragma unroll
    for (int i = 0; i < 4; i++) {
        int idx = t + 256 * i;
        int d = idx >> 4, sc = idx & 15;
        unsigned short tmp[8];
        #pragma unroll
        for (int j = 0; j < 8; j++) tmp[j] = sb[(sc * 8 + j) * 66 + d];
        *(uint4*)&Vt[((size_t)z * 64 + d) * L + s0 + sc * 8] = *(uint4*)tmp;
    }
}

// ---------------- fused attention + PV, register-direct K/V -----------------
// Phase 1 (barrier-free): each wave's K-fragments are per-lane 16B loads from
// L2 (rows (u*4+w)*16+l15); bias float4 streams fused per stage; compiler
// software-pipelines the fully unrolled 8 stages.
// Phase 2: V-fragments per-lane from Vt (L2); only p_sh needs LDS + one raw
// s_barrier + lgkmcnt(0) per stage (double-buffered); V prefetch stays in
// flight across the barrier (no vmcnt drain).
__global__ __launch_bounds__(256, 3) void attn_pv_kernel(
        const unsigned short* __restrict__ Qm, const unsigned short* __restrict__ Km,
        const unsigned short* __restrict__ Vt,
        const float* __restrict__ pos_bias, const float* __restrict__ postag,
        const float* __restrict__ lsm, float* __restrict__ attn_out,
        unsigned short* __restrict__ ctx16) {
    __shared__ __align__(16) unsigned short q_sh[16][72];
    __shared__ __align__(16) unsigned short p_sh[2][16][136];  // dbuf P chunk
    __shared__ float lsm_sh[1024];
    __shared__ float redA[16][4], redB[16][4];

    int t = threadIdx.x, lane = t & 63, w = t >> 6;
    int quad = lane >> 4, l15 = lane & 15;
    int qt = blockIdx.x & 63;
    int bh = blockIdx.x >> 6;
    int b = bh >> 4, h = bh & 15;
    int q0 = qt * 16;
    int q = q0 + l15;
    size_t base = (size_t)b * L * D + (size_t)h * DK;

    if (t < 128) {
        int r = t >> 3, c8 = t & 7;
        *(uint4*)&q_sh[r][c8 * 8] = *(const uint4*)&Qm[base + (size_t)(q0 + r) * D + c8 * 8];
    }
    ((float4*)lsm_sh)[t] = ((const float4*)(lsm + b * L))[t];
    __syncthreads();
    bf16x8 qb0 = *(const bf16x8*)&q_sh[l15][quad * 8];
    bf16x8 qb1 = *(const bf16x8*)&q_sh[l15][32 + quad * 8];

    const float* pbp = pos_bias + ((size_t)h * L + q) * L;
    const float* ptp = postag + ((size_t)bh * L + q) * L;
    // per-lane K fragment pointers: rows (u*4+w)*16 + l15, k-offset quad*8
    const unsigned short* kp0 = Km + base + (size_t)((w) * 16 + l15) * D + quad * 8;
    const unsigned short* kp1 = Km + base + (size_t)((4 + w) * 16 + l15) * D + quad * 8;

    f32x4 acc[16] = {};
    // ---- Phase 1: barrier-free S^T, 8 stages fully unrolled ---------------
    #pragma unroll
    for (int st = 0; st < 8; st++) {
        size_t ko = (size_t)st * 128 * D;
        bf16x8 ka00 = *(const bf16x8*)(kp0 + ko);
        bf16x8 ka01 = *(const bf16x8*)(kp0 + ko + 32);
        bf16x8 ka10 = *(const bf16x8*)(kp1 + ko);
        bf16x8 ka11 = *(const bf16x8*)(kp1 + ko + 32);
        int s_u0 = st * 128 + w * 16 + quad * 4;
        int s_u1 = s_u0 + 64;
        float4 pb0 = *(const float4*)(pbp + s_u0);
        float4 pt0 = *(const float4*)(ptp + s_u0);
        float4 pb1 = *(const float4*)(pbp + s_u1);
        float4 pt1 = *(const float4*)(ptp + s_u1);
        float4 l0 = *(const float4*)&lsm_sh[s_u0];
        float4 l1 = *(const float4*)&lsm_sh[s_u1];
        int ti0 = 2 * st, ti1 = 2 * st + 1;
        acc[ti0] = __builtin_amdgcn_mfma_f32_16x16x32_bf16(ka00, qb0, acc[ti0], 0, 0, 0);
        acc[ti0] = __builtin_amdgcn_mfma_f32_16x16x32_bf16(ka01, qb1, acc[ti0], 0, 0, 0);
        acc[ti1] = __builtin_amdgcn_mfma_f32_16x16x32_bf16(ka10, qb0, acc[ti1], 0, 0, 0);
        acc[ti1] = __builtin_amdgcn_mfma_f32_16x16x32_bf16(ka11, qb1, acc[ti1], 0, 0, 0);
        acc[ti0][0] = acc[ti0][0] * 0.125f + (pb0.x + pt0.x + l0.x);
        acc[ti0][1] = acc[ti0][1] * 0.125f + (pb0.y + pt0.y + l0.y);
        acc[ti0][2] = acc[ti0][2] * 0.125f + (pb0.z + pt0.z + l0.z);
        acc[ti0][3] = acc[ti0][3] * 0.125f + (pb0.w + pt0.w + l0.w);
        acc[ti1][0] = acc[ti1][0] * 0.125f + (pb1.x + pt1.x + l1.x);
        acc[ti1][1] = acc[ti1][1] * 0.125f + (pb1.y + pt1.y + l1.y);
        acc[ti1][2] = acc[ti1][2] * 0.125f + (pb1.z + pt1.z + l1.z);
        acc[ti1][3] = acc[ti1][3] * 0.125f + (pb1.w + pt1.w + l1.w);
    }
    // ---- softmax over s: per-lane -> quads (shfl 16,32) -> waves (LDS) ----
    float mx = -1e30f;
    #pragma unroll
    for (int ti = 0; ti < 16; ti++)
        #pragma unroll
        for (int rg = 0; rg < 4; rg++) mx = fmaxf(mx, acc[ti][rg]);
    mx = fmaxf(mx, __shfl_xor(mx, 16, 64));
    mx = fmaxf(mx, __shfl_xor(mx, 32, 64));
    if (quad == 0) redA[l15][w] = mx;
    __syncthreads();
    mx = fmaxf(fmaxf(redA[l15][0], redA[l15][1]), fmaxf(redA[l15][2], redA[l15][3]));
    float sum = 0.f;
    #pragma unroll
    for (int ti = 0; ti < 16; ti++)
        #pragma unroll
        for (int rg = 0; rg < 4; rg++) {
            float e = __expf(acc[ti][rg] - mx);
            acc[ti][rg] = e;
            sum += e;
        }
    sum += __shfl_xor(sum, 16, 64);
    sum += __shfl_xor(sum, 32, 64);
    if (quad == 0) redB[l15][w] = sum;
    __syncthreads();
    float inv = 1.0f / (redB[l15][0] + redB[l15][1] + redB[l15][2] + redB[l15][3]);
    // ---- write attn (float4 along s); keep normalized P in acc ------------
    #pragma unroll
    for (int ti = 0; ti < 16; ti++) {
        int s0 = (ti >> 1) * 128 + (ti & 1) * 64 + w * 16 + quad * 4;
        float4 o;
        o.x = acc[ti][0] * inv; o.y = acc[ti][1] * inv;
        o.z = acc[ti][2] * inv; o.w = acc[ti][3] * inv;
        acc[ti][0] = o.x; acc[ti][1] = o.y; acc[ti][2] = o.z; acc[ti][3] = o.w;
        *(float4*)&attn_out[((size_t)bh * L + q) * L + s0] = o;
    }
    // ---- Phase 2: ctx = P V; V frags direct from L2, p_sh dbuf ------------
    const unsigned short* vpl = Vt + ((size_t)bh * 64 + w * 16 + l15) * L + quad * 8;
    f32x4 cacc = {};
    bf16x8 vcur[4];
    #pragma unroll
    for (int kk = 0; kk < 4; kk++)
        vcur[kk] = *(const bf16x8*)(vpl + kk * 32);
    #pragma unroll
    for (int st = 0; st < 8; st++) {
        #pragma unroll
        for (int u = 0; u < 2; u++) {
            f32x4 p = acc[2 * st + u];
            ushort4 pu;
            pu.x = f2bf(p[0]); pu.y = f2bf(p[1]); pu.z = f2bf(p[2]); pu.w = f2bf(p[3]);
            *(ushort4*)&p_sh[st & 1][l15][u * 64 + w * 16 + quad * 4] = pu;
        }
        bf16x8 vnext[4];
        if (st < 7) {
            #pragma unroll
            for (int kk = 0; kk < 4; kk++)
                vnext[kk] = *(const bf16x8*)(vpl + (st + 1) * 128 + kk * 32);
        }
        // p_sh visible to all waves; V prefetch stays in flight (no vmcnt)
        asm volatile("s_waitcnt lgkmcnt(0)" ::: "memory");
        __builtin_amdgcn_sched_barrier(0);
        __builtin_amdgcn_s_barrier();
        __builtin_amdgcn_sched_barrier(0);
        #pragma unroll
        for (int kk = 0; kk < 4; kk++) {
            bf16x8 pf = *(const bf16x8*)&p_sh[st & 1][l15][kk * 32 + quad * 8];
            cacc = __builtin_amdgcn_mfma_f32_16x16x32_bf16(pf, vcur[kk], cacc, 0, 0, 0);
        }
        if (st < 7) {
            #pragma unroll
            for (int kk = 0; kk < 4; kk++) vcur[kk] = vnext[kk];
        }
    }
    // ctx[d = w*16+l15][q = quad*4+rg] -> ctx16[(b*L + q0 + q)*D + h*64 + d]
    size_t cbase = ((size_t)b * L + q0) * D + (size_t)h * 64 + w * 16 + l15;
    #pragma unroll
    for (int rg = 0; rg < 4; rg++)
        ctx16[cbase + (size_t)(quad * 4 + rg) * D] = f2bf(cacc[rg]);
}

// ---------------- out GEMM: out = ctx @ Wo^T + bo + query, 64x64 tile ------
__global__ __launch_bounds__(256) void gemm_out(
        const unsigned short* __restrict__ A, const unsigned short* __restrict__ W,
        const float* __restrict__ bias, const float* __restrict__ res,
        float* __restrict__ C) {
    __shared__ __align__(16) unsigned short As[64 * 64];
    __shared__ __align__(16) unsigned short Ws[64 * 64];
    int t = threadIdx.x, lane = t & 63, w = t >> 6;
    int quad = lane >> 4, l15 = lane & 15;
    int bm = blockIdx.x * 64, bn = blockIdx.y * 64;
    int wm = (w >> 1) * 32, wn = (w & 1) * 32;
    f32x4 acc[2][2] = {};
    for (int k0 = 0; k0 < D; k0 += 64) {
        __syncthreads();
        const unsigned short* ap = A + (size_t)(bm + w * 16) * D + k0;
        const unsigned short* wp = W + (size_t)(bn + w * 16) * D + k0;
        #pragma unroll
        for (int i = 0; i < 2; i++) {
            int c = i * 64 + lane;
            int r = c >> 3, g = (c & 7) ^ (r & 7);
            glds16(ap + (size_t)r * D + g * 8, &As[w * 1024 + i * 512]);
            glds16(wp + (size_t)r * D + g * 8, &Ws[w * 1024 + i * 512]);
        }
        __syncthreads();
        #pragma unroll
        for (int k2 = 0; k2 < 2; k2++) {
            bf16x8 av[2], bw[2];
            #pragma unroll
            for (int i = 0; i < 2; i++) {
                int r = wm + i * 16 + l15;
                av[i] = *(const bf16x8*)&As[r * 64 + (((quad + 4 * k2) ^ (r & 7)) * 8)];
            }
            #pragma unroll
            for (int j = 0; j < 2; j++) {
                int r = wn + j * 16 + l15;
                bw[j] = *(const bf16x8*)&Ws[r * 64 + (((quad + 4 * k2) ^ (r & 7)) * 8)];
            }
            #pragma unroll
            for (int i = 0; i < 2; i++)
                #pragma unroll
                for (int j = 0; j < 2; j++)
                    acc[i][j] = __builtin_amdgcn_mfma_f32_16x16x32_bf16(av[i], bw[j], acc[i][j], 0, 0, 0);
        }
    }
    #pragma unroll
    for (int j = 0; j < 2; j++) {
        int col = bn + wn + j * 16 + l15;
        float bcol = bias[col];
        #pragma unroll
        for (int i = 0; i < 2; i++)
            #pragma unroll
            for (int rg = 0; rg < 4; rg++) {
                int row = bm + wm + i * 16 + quad * 4 + rg;
                C[(size_t)row * D + col] = acc[i][j][rg] + bcol + res[(size_t)row * D + col];
            }
    }
}

extern "C" void kernel_launch(void* const* d_in, const int* in_sizes, int n_in,
                              void* d_out, int out_size, void* d_ws, size_t ws_size,
                              hipStream_t stream) {
    (void)in_sizes; (void)n_in; (void)out_size; (void)ws_size;
    const float* query  = (const float*)d_in[0];
    const float* pos_b  = (const float*)d_in[1];
    const float* postag = (const float*)d_in[2];
    const float* lex    = (const float*)d_in[3];
    const int*   mask   = (const int*)d_in[4];
    const float* Wq = (const float*)d_in[5];
    const float* bq = (const float*)d_in[6];
    const float* Wk = (const float*)d_in[7];
    const float* bk = (const float*)d_in[8];
    const float* Wv = (const float*)d_in[9];
    const float* bv = (const float*)d_in[10];
    const float* Wo = (const float*)d_in[11];
    const float* bo = (const float*)d_in[12];
    const float* gamma = (const float*)d_in[13];
    const float* beta  = (const float*)d_in[14];

    float* out  = (float*)d_out;                 // (B,L,D)
    float* attn = out + (size_t)B * L * D;       // (B,H,L,L)

    unsigned short* ws16 = (unsigned short*)d_ws;
    const size_t NE = (size_t)M * D;
    unsigned short* qn16  = ws16;
    unsigned short* q16   = ws16 + NE;
    unsigned short* W16   = ws16 + 2 * NE;       // 4*DD
    unsigned short* Qm16  = W16 + 4 * (size_t)DD;
    unsigned short* Km16  = Qm16 + NE;
    unsigned short* Vm16  = Km16 + NE;
    unsigned short* Vt16  = Vm16 + NE;           // [32][64][1024]
    unsigned short* ctx16 = Vt16 + NE;
    float* lsm = (float*)(ctx16 + NE);           // (B,L) fused lex+mask

    ln2_kernel<<<M, 256, 0, stream>>>(query, gamma, beta, lex, mask, qn16, q16, lsm);
    wconv_kernel<<<dim3(DD / 1024, 4), 256, 0, stream>>>(Wq, Wk, Wv, Wo, W16);
    gemm_qkv<<<dim3(24, 16), 256, 0, stream>>>(qn16, q16, W16, bq, bk, bv,
                                               Qm16, Km16, Vm16);
    vtrans_kernel<<<dim3(8, 32), 256, 0, stream>>>(Vm16, Vt16);
    attn_pv_kernel<<<B * H * (L / 16), 256, 0, stream>>>(Qm16, Km16, Vt16,
                                                         pos_b, postag, lsm,
                                                         attn, ctx16);
    gemm_out<<<dim3(32, 16), 256, 0, stream>>>(ctx16, W16 + 3 * (size_t)DD, bo, query, out);
}

// Round 4
// 402.198 us; speedup vs baseline: 1.0744x; 1.0744x over previous
//
#include <hip/hip_runtime.h>
#include <hip/hip_bf16.h>
#include <math.h>

constexpr int B = 2, L = 1024, D = 1024, H = 16, DK = 64;
constexpr int M = B * L;           // 2048 rows
constexpr int DD = D * D;

typedef __attribute__((ext_vector_type(8))) short bf16x8;
typedef __attribute__((ext_vector_type(4))) float f32x4;

#define SB0() __builtin_amdgcn_sched_barrier(0)

__device__ inline unsigned short f2bf(float f) {
    __hip_bfloat16 h = __float2bfloat16(f);
    return __builtin_bit_cast(unsigned short, h);
}

// async global->LDS, 16B per lane; LDS dest = base + lane*16 (wave-uniform base)
__device__ inline void glds16(const void* g, void* l) {
    __builtin_amdgcn_global_load_lds((const __attribute__((address_space(1))) void*)g,
                                     (__attribute__((address_space(3))) void*)l,
                                     16, 0, 0);
}

// ---------------- LayerNorm + lsm: qn16 = LN(query), q16 = bf16(query) ------
__global__ __launch_bounds__(256) void ln2_kernel(const float* __restrict__ x,
                                                  const float* __restrict__ gamma,
                                                  const float* __restrict__ beta,
                                                  const float* __restrict__ lex,
                                                  const int* __restrict__ mask,
                                                  unsigned short* __restrict__ qn16,
                                                  unsigned short* __restrict__ q16,
                                                  float* __restrict__ lsmout) {
    int row = blockIdx.x;
    int t = threadIdx.x;
    if (t == 0) lsmout[row] = mask[row] ? lex[row] : -1e30f;
    const float4 v = ((const float4*)(x + (size_t)row * D))[t];
    float s  = v.x + v.y + v.z + v.w;
    float sq = v.x*v.x + v.y*v.y + v.z*v.z + v.w*v.w;
    #pragma unroll
    for (int m = 32; m >= 1; m >>= 1) {
        s  += __shfl_xor(s, m, 64);
        sq += __shfl_xor(sq, m, 64);
    }
    __shared__ float rs[4], rq[4];
    int wid = t >> 6;
    if ((t & 63) == 0) { rs[wid] = s; rq[wid] = sq; }
    __syncthreads();
    s  = rs[0] + rs[1] + rs[2] + rs[3];
    sq = rq[0] + rq[1] + rq[2] + rq[3];
    float mean = s * (1.0f / D);
    float var  = sq * (1.0f / D) - mean * mean;
    float rstd = rsqrtf(var + 1e-6f);
    float4 g  = ((const float4*)gamma)[t];
    float4 bb = ((const float4*)beta)[t];
    ushort4 on, oq;
    on.x = f2bf((v.x - mean) * rstd * g.x + bb.x);
    on.y = f2bf((v.y - mean) * rstd * g.y + bb.y);
    on.z = f2bf((v.z - mean) * rstd * g.z + bb.z);
    on.w = f2bf((v.w - mean) * rstd * g.w + bb.w);
    oq.x = f2bf(v.x); oq.y = f2bf(v.y); oq.z = f2bf(v.z); oq.w = f2bf(v.w);
    ((ushort4*)(qn16 + (size_t)row * D))[t] = on;
    ((ushort4*)(q16  + (size_t)row * D))[t] = oq;
}

// ---------------- weight cast: 4 x (D,D) fp32 -> bf16 ----------------------
__global__ __launch_bounds__(256) void wconv_kernel(const float* __restrict__ Wq,
                                                    const float* __restrict__ Wk,
                                                    const float* __restrict__ Wv,
                                                    const float* __restrict__ Wo,
                                                    unsigned short* __restrict__ out) {
    const float* src = (blockIdx.y == 0) ? Wq : (blockIdx.y == 1) ? Wk
                       : (blockIdx.y == 2) ? Wv : Wo;
    size_t i = (size_t)blockIdx.x * 256 + threadIdx.x;
    float4 v = ((const float4*)src)[i];
    ushort4 o;
    o.x = f2bf(v.x); o.y = f2bf(v.y); o.z = f2bf(v.z); o.w = f2bf(v.w);
    ((ushort4*)(out + (size_t)blockIdx.y * DD))[i] = o;
}

// ---------------- fused QKV GEMM: 128x128 tile, BK=64, global_load_lds ------
__global__ __launch_bounds__(256) void gemm_qkv(
        const unsigned short* __restrict__ qn16, const unsigned short* __restrict__ q16,
        const unsigned short* __restrict__ W,
        const float* __restrict__ bq, const float* __restrict__ bk,
        const float* __restrict__ bv,
        unsigned short* __restrict__ Qm, unsigned short* __restrict__ Km,
        unsigned short* __restrict__ Vm) {
    __shared__ __align__(16) unsigned short As[128 * 64];
    __shared__ __align__(16) unsigned short Ws[128 * 64];
    int t = threadIdx.x, lane = t & 63, w = t >> 6;
    int quad = lane >> 4, l15 = lane & 15;
    int nt = blockIdx.x;                 // 0..23
    int bm = blockIdx.y * 128;
    const unsigned short* A = (nt < 8) ? qn16 : q16;
    const float* bias = (nt < 8) ? bq : ((nt < 16) ? bk : bv);
    unsigned short* Cout = (nt < 8) ? Qm : ((nt < 16) ? Km : Vm);
    int bn_local = (nt & 7) * 128;
    int wm = (w >> 1) * 64, wn = (w & 1) * 64;
    f32x4 acc[4][4] = {};
    for (int k0 = 0; k0 < D; k0 += 64) {
        __syncthreads();
        const unsigned short* ap = A + (size_t)(bm + w * 32) * D + k0;
        const unsigned short* wp = W + (size_t)(nt * 128 + w * 32) * D + k0;
        #pragma unroll
        for (int i = 0; i < 4; i++) {
            int c = i * 64 + lane;
            int r = c >> 3, g = (c & 7) ^ (r & 7);
            glds16(ap + (size_t)r * D + g * 8, &As[w * 2048 + i * 512]);
            glds16(wp + (size_t)r * D + g * 8, &Ws[w * 2048 + i * 512]);
        }
        __syncthreads();
        #pragma unroll
        for (int k2 = 0; k2 < 2; k2++) {
            bf16x8 av[4], bw[4];
            #pragma unroll
            for (int i = 0; i < 4; i++) {
                int r = wm + i * 16 + l15;
                av[i] = *(const bf16x8*)&As[r * 64 + (((quad + 4 * k2) ^ (r & 7)) * 8)];
            }
            #pragma unroll
            for (int j = 0; j < 4; j++) {
                int r = wn + j * 16 + l15;
                bw[j] = *(const bf16x8*)&Ws[r * 64 + (((quad + 4 * k2) ^ (r & 7)) * 8)];
            }
            #pragma unroll
            for (int i = 0; i < 4; i++)
                #pragma unroll
                for (int j = 0; j < 4; j++)
                    acc[i][j] = __builtin_amdgcn_mfma_f32_16x16x32_bf16(av[i], bw[j], acc[i][j], 0, 0, 0);
        }
    }
    #pragma unroll
    for (int j = 0; j < 4; j++) {
        int col = bn_local + wn + j * 16 + l15;
        float bcol = bias[col];
        #pragma unroll
        for (int i = 0; i < 4; i++)
            #pragma unroll
            for (int rg = 0; rg < 4; rg++) {
                int row = bm + wm + i * 16 + quad * 4 + rg;
                Cout[(size_t)row * D + col] = f2bf(acc[i][j][rg] + bcol);
            }
    }
}

// ---------------- V transpose: Vm [b,s,h*64+d] -> Vt [bh][d][s] ------------
__global__ __launch_bounds__(256) void vtrans_kernel(const unsigned short* __restrict__ Vm,
                                                     unsigned short* __restrict__ Vt) {
    __shared__ unsigned short sb[128 * 66];
    int t = threadIdx.x;
    int z = blockIdx.y;
    int b = z >> 4, h = z & 15;
    int s0 = blockIdx.x * 128;
    size_t base = (size_t)b * L * D + (size_t)h * 64;
    #pragma unroll
    for (int i = 0; i < 4; i++) {
        int idx = t + 256 * i;
        int r = idx >> 3, c8 = idx & 7;
        uint4 vv = *(const uint4*)&Vm[base + (size_t)(s0 + r) * D + c8 * 8];
        unsigned int* sp = (unsigned int*)&sb[r * 66 + c8 * 8];
        sp[0] = vv.x; sp[1] = vv.y; sp[2] = vv.z; sp[3] = vv.w;
    }
    __syncthreads();
    #pragma unroll
    for (int i = 0; i < 4; i++) {
        int idx = t + 256 * i;
        int d = idx >> 4, sc = idx & 15;
        unsigned short tmp[8];
        #pragma unroll
        for (int j = 0; j < 8; j++) tmp[j] = sb[(sc * 8 + j) * 66 + d];
        *(uint4*)&Vt[((size_t)z * 64 + d) * L + s0 + sc * 8] = *(uint4*)tmp;
    }
}

// ---------------- fused attention + PV, LDS-parked prefetch, no drains ------
// Phase 1 (no block barriers): wave w privately stages & computes s-rows
// [st*128 + w*32, +32). K and both bias streams double-buffered in LDS via
// global_load_lds; counted s_waitcnt vmcnt(8) keeps next-stage loads in
// flight across compute. All VMEM in sched_barrier(0)-fenced groups.
// Phase 2: private V staging dbuf (vmcnt(4)); p_sh single-buffered with two
// raw s_barriers/stage (lgkmcnt(0) only -- V prefetch crosses the barrier).
__global__ __launch_bounds__(256, 2) void attn_pv_kernel(
        const unsigned short* __restrict__ Qm, const unsigned short* __restrict__ Km,
        const unsigned short* __restrict__ Vt,
        const float* __restrict__ pos_bias, const float* __restrict__ postag,
        const float* __restrict__ lsm, float* __restrict__ attn_out,
        unsigned short* __restrict__ ctx16) {
    // pool layout (shorts): [0,16384) K dbuf: buf*8192 + w*2048  (32 rows x 64)
    //                       [16384,32768) bias dbuf: +buf*8192 + w*2048
    //                              (pb [16][32]f32 = 1024 shorts, pt at +1024)
    // phase 2 overlays [0,16384) as V dbuf: buf*8192 + w*2048 (16 rows x 128)
    __shared__ __align__(16) unsigned short pool[32768];
    __shared__ __align__(16) unsigned short p_sh[16][136];
    __shared__ __align__(16) unsigned short q_sh[16][72];
    __shared__ float lsm_sh[1024];
    __shared__ float redA[16][4], redB[16][4];

    int t = threadIdx.x, lane = t & 63, w = t >> 6;
    int quad = lane >> 4, l15 = lane & 15;
    int qt = blockIdx.x & 63;
    int bh = blockIdx.x >> 6;
    int b = bh >> 4, h = bh & 15;
    int q0 = qt * 16;
    int q = q0 + l15;
    size_t base = (size_t)b * L * D + (size_t)h * DK;

    if (t < 128) {
        int r = t >> 3, c8 = t & 7;
        *(uint4*)&q_sh[r][c8 * 8] = *(const uint4*)&Qm[base + (size_t)(q0 + r) * D + c8 * 8];
    }
    ((float4*)lsm_sh)[t] = ((const float4*)(lsm + b * L))[t];
    __syncthreads();                       // drains q/lsm loads (vmcnt -> 0)
    bf16x8 qb0 = *(const bf16x8*)&q_sh[l15][quad * 8];
    bf16x8 qb1 = *(const bf16x8*)&q_sh[l15][32 + quad * 8];

    const float* pbQ = pos_bias + ((size_t)h * L + q0) * L;   // row q0, this head
    const float* ptQ = postag + ((size_t)bh * L + q0) * L;

    f32x4 acc[16] = {};
    // ---- Phase 1 prologue: stage st=0 into buf 0 --------------------------
    SB0();
    {
        const unsigned short* kpn = Km + base + (size_t)(w * 32) * D;
        #pragma unroll
        for (int i = 0; i < 4; i++) {
            int r = i * 8 + (lane >> 3);
            int g = (lane & 7) ^ (r & 7);
            glds16(kpn + (size_t)r * D + g * 8, &pool[w * 2048 + i * 512]);
        }
    }
    SB0();
    {
        int rb = lane >> 3;
        int gb = (lane & 7) ^ rb;
        #pragma unroll
        for (int i = 0; i < 2; i++) {
            glds16(pbQ + (size_t)(i * 8 + rb) * L + w * 32 + gb * 4,
                   &pool[16384 + w * 2048 + i * 512]);
            glds16(ptQ + (size_t)(i * 8 + rb) * L + w * 32 + gb * 4,
                   &pool[16384 + w * 2048 + 1024 + i * 512]);
        }
    }
    SB0();
    // ---- Phase 1 main loop: no block barriers, counted vmcnt --------------
    #pragma unroll
    for (int st = 0; st < 8; st++) {
        int bc = st & 1, bn = bc ^ 1;
        if (st < 7) {
            SB0();
            const unsigned short* kpn = Km + base + (size_t)((st + 1) * 128 + w * 32) * D;
            #pragma unroll
            for (int i = 0; i < 4; i++) {
                int r = i * 8 + (lane >> 3);
                int g = (lane & 7) ^ (r & 7);
                glds16(kpn + (size_t)r * D + g * 8, &pool[bn * 8192 + w * 2048 + i * 512]);
            }
            SB0();
            {
                int rb = lane >> 3;
                int gb = (lane & 7) ^ rb;
                #pragma unroll
                for (int i = 0; i < 2; i++) {
                    glds16(pbQ + (size_t)(i * 8 + rb) * L + (st + 1) * 128 + w * 32 + gb * 4,
                           &pool[16384 + bn * 8192 + w * 2048 + i * 512]);
                    glds16(ptQ + (size_t)(i * 8 + rb) * L + (st + 1) * 128 + w * 32 + gb * 4,
                           &pool[16384 + bn * 8192 + w * 2048 + 1024 + i * 512]);
                }
            }
            SB0();
            asm volatile("s_waitcnt vmcnt(8)" ::: "memory");   // stage st landed
        } else {
            SB0();
            asm volatile("s_waitcnt vmcnt(0)" ::: "memory");
        }
        SB0();
        int r7 = l15 & 7;
        const unsigned short* kB = &pool[bc * 8192 + w * 2048];
        bf16x8 ka00 = *(const bf16x8*)&kB[l15 * 64 + ((quad ^ r7) * 8)];
        bf16x8 ka01 = *(const bf16x8*)&kB[l15 * 64 + (((quad + 4) ^ r7) * 8)];
        bf16x8 ka10 = *(const bf16x8*)&kB[(16 + l15) * 64 + ((quad ^ r7) * 8)];
        bf16x8 ka11 = *(const bf16x8*)&kB[(16 + l15) * 64 + (((quad + 4) ^ r7) * 8)];
        const float* pbL = (const float*)&pool[16384 + bc * 8192 + w * 2048];
        const float* ptL = (const float*)&pool[16384 + bc * 8192 + w * 2048 + 1024];
        float4 pb0 = *(const float4*)&pbL[l15 * 32 + ((quad ^ r7) * 4)];
        float4 pb1 = *(const float4*)&pbL[l15 * 32 + (((quad + 4) ^ r7) * 4)];
        float4 pt0 = *(const float4*)&ptL[l15 * 32 + ((quad ^ r7) * 4)];
        float4 pt1 = *(const float4*)&ptL[l15 * 32 + (((quad + 4) ^ r7) * 4)];
        int s_u0 = st * 128 + w * 32 + quad * 4;
        float4 l0 = *(const float4*)&lsm_sh[s_u0];
        float4 l1 = *(const float4*)&lsm_sh[s_u0 + 16];
        int ti0 = 2 * st, ti1 = ti0 + 1;
        acc[ti0] = __builtin_amdgcn_mfma_f32_16x16x32_bf16(ka00, qb0, acc[ti0], 0, 0, 0);
        acc[ti0] = __builtin_amdgcn_mfma_f32_16x16x32_bf16(ka01, qb1, acc[ti0], 0, 0, 0);
        acc[ti1] = __builtin_amdgcn_mfma_f32_16x16x32_bf16(ka10, qb0, acc[ti1], 0, 0, 0);
        acc[ti1] = __builtin_amdgcn_mfma_f32_16x16x32_bf16(ka11, qb1, acc[ti1], 0, 0, 0);
        acc[ti0][0] = acc[ti0][0] * 0.125f + (pb0.x + pt0.x + l0.x);
        acc[ti0][1] = acc[ti0][1] * 0.125f + (pb0.y + pt0.y + l0.y);
        acc[ti0][2] = acc[ti0][2] * 0.125f + (pb0.z + pt0.z + l0.z);
        acc[ti0][3] = acc[ti0][3] * 0.125f + (pb0.w + pt0.w + l0.w);
        acc[ti1][0] = acc[ti1][0] * 0.125f + (pb1.x + pt1.x + l1.x);
        acc[ti1][1] = acc[ti1][1] * 0.125f + (pb1.y + pt1.y + l1.y);
        acc[ti1][2] = acc[ti1][2] * 0.125f + (pb1.z + pt1.z + l1.z);
        acc[ti1][3] = acc[ti1][3] * 0.125f + (pb1.w + pt1.w + l1.w);
    }
    // ---- softmax over s: per-lane -> quads (shfl 16,32) -> waves (LDS) ----
    float mx = -1e30f;
    #pragma unroll
    for (int ti = 0; ti < 16; ti++)
        #pragma unroll
        for (int rg = 0; rg < 4; rg++) mx = fmaxf(mx, acc[ti][rg]);
    mx = fmaxf(mx, __shfl_xor(mx, 16, 64));
    mx = fmaxf(mx, __shfl_xor(mx, 32, 64));
    if (quad == 0) redA[l15][w] = mx;
    __syncthreads();
    mx = fmaxf(fmaxf(redA[l15][0], redA[l15][1]), fmaxf(redA[l15][2], redA[l15][3]));
    float sum = 0.f;
    #pragma unroll
    for (int ti = 0; ti < 16; ti++)
        #pragma unroll
        for (int rg = 0; rg < 4; rg++) {
            float e = __expf(acc[ti][rg] - mx);
            acc[ti][rg] = e;
            sum += e;
        }
    sum += __shfl_xor(sum, 16, 64);
    sum += __shfl_xor(sum, 32, 64);
    if (quad == 0) redB[l15][w] = sum;
    __syncthreads();
    float inv = 1.0f / (redB[l15][0] + redB[l15][1] + redB[l15][2] + redB[l15][3]);
    // ---- write attn (float4 along s); keep normalized P in acc ------------
    #pragma unroll
    for (int ti = 0; ti < 16; ti++) {
        int s0 = (ti >> 1) * 128 + w * 32 + (ti & 1) * 16 + quad * 4;
        float4 o;
        o.x = acc[ti][0] * inv; o.y = acc[ti][1] * inv;
        o.z = acc[ti][2] * inv; o.w = acc[ti][3] * inv;
        acc[ti][0] = o.x; acc[ti][1] = o.y; acc[ti][2] = o.z; acc[ti][3] = o.w;
        *(float4*)&attn_out[((size_t)bh * L + q) * L + s0] = o;
    }
    // ---- Phase 2: ctx = P V; private V dbuf via glds, p_sh + 2 barriers ---
    f32x4 cacc = {};
    const unsigned short* vbase = Vt + ((size_t)bh * 64 + w * 16) * L;
    SB0();
    #pragma unroll
    for (int i = 0; i < 4; i++) {          // V stage 0 -> buf 0
        int r = i * 4 + (lane >> 4);
        int g = (lane & 15) ^ (r & 7);
        glds16(vbase + (size_t)r * L + g * 8, &pool[w * 2048 + i * 512]);
    }
    SB0();
    #pragma unroll
    for (int st = 0; st < 8; st++) {
        int bc = st & 1;
        #pragma unroll
        for (int u = 0; u < 2; u++) {
            f32x4 p = acc[2 * st + u];
            ushort4 pu;
            pu.x = f2bf(p[0]); pu.y = f2bf(p[1]); pu.z = f2bf(p[2]); pu.w = f2bf(p[3]);
            *(ushort4*)&p_sh[l15][w * 32 + u * 16 + quad * 4] = pu;
        }
        if (st < 7) {
            SB0();
            #pragma unroll
            for (int i = 0; i < 4; i++) {
                int r = i * 4 + (lane >> 4);
                int g = (lane & 15) ^ (r & 7);
                glds16(vbase + (size_t)r * L + (st + 1) * 128 + g * 8,
                       &pool[(bc ^ 1) * 8192 + w * 2048 + i * 512]);
            }
            SB0();
            asm volatile("s_waitcnt vmcnt(4)" ::: "memory");   // V stage st landed
        } else {
            SB0();
            asm volatile("s_waitcnt vmcnt(0)" ::: "memory");
        }
        asm volatile("s_waitcnt lgkmcnt(0)" ::: "memory");     // p_sh writes visible
        SB0();
        __builtin_amdgcn_s_barrier();
        SB0();
        const unsigned short* vB = &pool[bc * 8192 + w * 2048];
        #pragma unroll
        for (int kk = 0; kk < 4; kk++) {
            bf16x8 vf = *(const bf16x8*)&vB[l15 * 128 + (((kk * 4 + quad) ^ (l15 & 7)) * 8)];
            bf16x8 pf = *(const bf16x8*)&p_sh[l15][kk * 32 + quad * 8];
            cacc = __builtin_amdgcn_mfma_f32_16x16x32_bf16(pf, vf, cacc, 0, 0, 0);
        }
        SB0();
        __builtin_amdgcn_s_barrier();      // all reads done before next p write
        SB0();
    }
    // ctx[d = w*16+l15][q = quad*4+rg] -> ctx16[(b*L + q0 + q)*D + h*64 + d]
    size_t cbase = ((size_t)b * L + q0) * D + (size_t)h * 64 + w * 16 + l15;
    #pragma unroll
    for (int rg = 0; rg < 4; rg++)
        ctx16[cbase + (size_t)(quad * 4 + rg) * D] = f2bf(cacc[rg]);
}

// ---------------- out GEMM: out = ctx @ Wo^T + bo + query, 64x64 tile ------
__global__ __launch_bounds__(256) void gemm_out(
        const unsigned short* __restrict__ A, const unsigned short* __restrict__ W,
        const float* __restrict__ bias, const float* __restrict__ res,
        float* __restrict__ C) {
    __shared__ __align__(16) unsigned short As[64 * 64];
    __shared__ __align__(16) unsigned short Ws[64 * 64];
    int t = threadIdx.x, lane = t & 63, w = t >> 6;
    int quad = lane >> 4, l15 = lane & 15;
    int bm = blockIdx.x * 64, bn = blockIdx.y * 64;
    int wm = (w >> 1) * 32, wn = (w & 1) * 32;
    f32x4 acc[2][2] = {};
    for (int k0 = 0; k0 < D; k0 += 64) {
        __syncthreads();
        const unsigned short* ap = A + (size_t)(bm + w * 16) * D + k0;
        const unsigned short* wp = W + (size_t)(bn + w * 16) * D + k0;
        #pragma unroll
        for (int i = 0; i < 2; i++) {
            int c = i * 64 + lane;
            int r = c >> 3, g = (c & 7) ^ (r & 7);
            glds16(ap + (size_t)r * D + g * 8, &As[w * 1024 + i * 512]);
            glds16(wp + (size_t)r * D + g * 8, &Ws[w * 1024 + i * 512]);
        }
        __syncthreads();
        #pragma unroll
        for (int k2 = 0; k2 < 2; k2++) {
            bf16x8 av[2], bw[2];
            #pragma unroll
            for (int i = 0; i < 2; i++) {
                int r = wm + i * 16 + l15;
                av[i] = *(const bf16x8*)&As[r * 64 + (((quad + 4 * k2) ^ (r & 7)) * 8)];
            }
            #pragma unroll
            for (int j = 0; j < 2; j++) {
                int r = wn + j * 16 + l15;
                bw[j] = *(const bf16x8*)&Ws[r * 64 + (((quad + 4 * k2) ^ (r & 7)) * 8)];
            }
            #pragma unroll
            for (int i = 0; i < 2; i++)
                #pragma unroll
                for (int j = 0; j < 2; j++)
                    acc[i][j] = __builtin_amdgcn_mfma_f32_16x16x32_bf16(av[i], bw[j], acc[i][j], 0, 0, 0);
        }
    }
    #pragma unroll
    for (int j = 0; j < 2; j++) {
        int col = bn + wn + j * 16 + l15;
        float bcol = bias[col];
        #pragma unroll
        for (int i = 0; i < 2; i++)
            #pragma unroll
            for (int rg = 0; rg < 4; rg++) {
                int row = bm + wm + i * 16 + quad * 4 + rg;
                C[(size_t)row * D + col] = acc[i][j][rg] + bcol + res[(size_t)row * D + col];
            }
    }
}

extern "C" void kernel_launch(void* const* d_in, const int* in_sizes, int n_in,
                              void* d_out, int out_size, void* d_ws, size_t ws_size,
                              hipStream_t stream) {
    (void)in_sizes; (void)n_in; (void)out_size; (void)ws_size;
    const float* query  = (const float*)d_in[0];
    const float* pos_b  = (const float*)d_in[1];
    const float* postag = (const float*)d_in[2];
    const float* lex    = (const float*)d_in[3];
    const int*   mask   = (const int*)d_in[4];
    const float* Wq = (const float*)d_in[5];
    const float* bq = (const float*)d_in[6];
    const float* Wk = (const float*)d_in[7];
    const float* bk = (const float*)d_in[8];
    const float* Wv = (const float*)d_in[9];
    const float* bv = (const float*)d_in[10];
    const float* Wo = (const float*)d_in[11];
    const float* bo = (const float*)d_in[12];
    const float* gamma = (const float*)d_in[13];
    const float* beta  = (const float*)d_in[14];

    float* out  = (float*)d_out;                 // (B,L,D)
    float* attn = out + (size_t)B * L * D;       // (B,H,L,L)

    unsigned short* ws16 = (unsigned short*)d_ws;
    const size_t NE = (size_t)M * D;
    unsigned short* qn16  = ws16;
    unsigned short* q16   = ws16 + NE;
    unsigned short* W16   = ws16 + 2 * NE;       // 4*DD
    unsigned short* Qm16  = W16 + 4 * (size_t)DD;
    unsigned short* Km16  = Qm16 + NE;
    unsigned short* Vm16  = Km16 + NE;
    unsigned short* Vt16  = Vm16 + NE;           // [32][64][1024]
    unsigned short* ctx16 = Vt16 + NE;
    float* lsm = (float*)(ctx16 + NE);           // (B,L) fused lex+mask

    ln2_kernel<<<M, 256, 0, stream>>>(query, gamma, beta, lex, mask, qn16, q16, lsm);
    wconv_kernel<<<dim3(DD / 1024, 4), 256, 0, stream>>>(Wq, Wk, Wv, Wo, W16);
    gemm_qkv<<<dim3(24, 16), 256, 0, stream>>>(qn16, q16, W16, bq, bk, bv,
                                               Qm16, Km16, Vm16);
    vtrans_kernel<<<dim3(8, 32), 256, 0, stream>>>(Vm16, Vt16);
    attn_pv_kernel<<<B * H * (L / 16), 256, 0, stream>>>(Qm16, Km16, Vt16,
                                                         pos_b, postag, lsm,
                                                         attn, ctx16);
    gemm_out<<<dim3(32, 16), 256, 0, stream>>>(ctx16, W16 + 3 * (size_t)DD, bo, query, out);
}